// Round 5
// baseline (840.901 us; speedup 1.0000x reference)
//
#include <hip/hip_runtime.h>
#include <hip/hip_cooperative_groups.h>
#include <math.h>

namespace cg = cooperative_groups;

// Problem constants
#define BB   16
#define CCH  512
#define HWN  4608      // H*W = 96*48
#define HW4  1152      // HWN/4
#define HW2  2304      // HWN/2
#define NSE  32
#define BN_EPS 1e-5f

#define NBLK 576       // 16 b x 4 c-chunks x 9 p-blocks; ~2.25 blocks/CU
#define NTHR 256       // 4 waves

typedef float f32x4 __attribute__((ext_vector_type(4)));

// ---------------------------------------------------------------------------
// Fused cooperative kernel: 5 phases, 4 grid syncs.
// ---------------------------------------------------------------------------
__global__ __launch_bounds__(NTHR, 4) void k_fused(
    const float* __restrict__ x,
    const float* __restrict__ se_w1, const float* __restrict__ se_b1,
    const float* __restrict__ se_w2, const float* __restrict__ se_b2,
    const float* __restrict__ g_w,   const float* __restrict__ g_b,
    const float* __restrict__ theta_w, const float* __restrict__ theta_b,
    const float* __restrict__ phi_w, const float* __restrict__ phi_b,
    const float* __restrict__ W_w,   const float* __restrict__ W_b,
    const float* __restrict__ bn_g,  const float* __restrict__ bn_b,
    const float* __restrict__ bn_m,  const float* __restrict__ bn_v,
    float* __restrict__ out,
    float* __restrict__ xp, float* __restrict__ tw, float* __restrict__ pw,
    float* __restrict__ gwv, float* __restrict__ th_part,
    float* __restrict__ ph_part, float* __restrict__ gx_part,
    float* __restrict__ ths)
{
    cg::grid_group grid = cg::this_grid();
    int blk = blockIdx.x, t = threadIdx.x;
    int wave = t >> 6, lane = t & 63;
    int gwid = blk * 4 + wave;               // 0..2303

    // ---- Phase A: xp[b,c] = spatial mean (one wave per row, grid-stride) --
    for (int r = gwid; r < BB * CCH; r += NBLK * 4) {
        const float4* xr = (const float4*)x + (size_t)r * HW4;
        float s = 0.f;
        #pragma unroll 6
        for (int k = 0; k < 18; ++k) {
            float4 v = xr[lane + k * 64];
            s += v.x + v.y + v.z + v.w;
        }
        #pragma unroll
        for (int off = 32; off > 0; off >>= 1)
            s += __shfl_down(s, off);
        if (lane == 0) xp[r] = s * (1.0f / (float)HWN);
    }
    __threadfence();
    grid.sync();

    // ---- Phase B: SE gate -> folded projection weights (blocks 0..15) -----
    if (blk < BB) {
        __shared__ float xs[CCH];
        __shared__ float hs[NSE];
        xs[t]       = xp[blk * CCH + t];
        xs[t + 256] = xp[blk * CCH + 256 + t];
        __syncthreads();
        #pragma unroll
        for (int i = 0; i < 8; ++i) {
            int h = wave * 8 + i;            // 4 waves x 8 = 32 hidden units
            const float* wr = se_w1 + h * CCH;
            float a = 0.f;
            #pragma unroll
            for (int k = 0; k < 8; ++k)
                a += wr[lane + 64 * k] * xs[lane + 64 * k];
            #pragma unroll
            for (int off = 32; off > 0; off >>= 1)
                a += __shfl_down(a, off);
            if (lane == 0) {
                a += se_b1[h];
                hs[h] = a > 0.f ? a : 0.f;   // relu
            }
        }
        __syncthreads();
        for (int c = t; c < CCH; c += NTHR) {
            float a = se_b2[c];
            const float* wr = se_w2 + c * NSE;
            #pragma unroll
            for (int j = 0; j < NSE; ++j) a += wr[j] * hs[j];
            float gate = 1.f / (1.f + expf(-a));   // sigmoid
            int idx = blk * CCH + c;
            tw[idx]  = gate * theta_w[c];
            pw[idx]  = gate * phi_w[c];
            gwv[idx] = gate * g_w[c];
        }
    }
    __threadfence();
    grid.sync();

    // ---- Phase C: partial channel contractions (all 576 blocks) -----------
    {
        int b = blk / 36, rem = blk % 36, ch = rem / 9, pb = rem % 9;
        int c0 = ch * 128;
        int p2 = pb * 256 + t;               // float2 index within row
        __shared__ float tws[128], pws[128], gws[128];
        if (t < 128) {
            int wi = b * CCH + c0 + t;
            tws[t] = tw[wi]; pws[t] = pw[wi]; gws[t] = gwv[wi];
        }
        __syncthreads();
        const float2* xr = (const float2*)x + (size_t)(b * CCH + c0) * HW2 + p2;
        float2 tha = {0.f, 0.f}, pha = {0.f, 0.f}, gxa = {0.f, 0.f};
        #pragma unroll 4
        for (int c = 0; c < 128; ++c) {
            float2 v = xr[(size_t)c * HW2];  // 256 lanes x 8B contiguous
            float tc = tws[c], pc = pws[c], gc = gws[c];
            tha.x += tc * v.x; tha.y += tc * v.y;
            pha.x += pc * v.x; pha.y += pc * v.y;
            gxa.x += gc * v.x; gxa.y += gc * v.y;
        }
        size_t oi = (size_t)(ch * BB + b) * HW2 + p2;
        ((float2*)th_part)[oi] = tha;
        ((float2*)ph_part)[oi] = pha;
        ((float2*)gx_part)[oi] = gxa;
    }
    __threadfence();
    grid.sync();

    // ---- Phase D: s[b] reduction + ths[b,p] (blocks 0..15) ----------------
    if (blk < BB) {
        __shared__ float red[NTHR];
        int b = blk;
        float pb_ = phi_b[0], gb_ = g_b[0];
        const float4* php = (const float4*)ph_part;
        const float4* gxp = (const float4*)gx_part;
        float acc = 0.f;
        for (int i = t; i < HW4; i += NTHR) {
            float4 ph = {pb_, pb_, pb_, pb_};
            float4 gx = {gb_, gb_, gb_, gb_};
            #pragma unroll
            for (int k = 0; k < 4; ++k) {
                size_t oi = (size_t)(k * BB + b) * HW4 + i;
                float4 pv = php[oi];
                float4 gv = gxp[oi];
                ph.x += pv.x; ph.y += pv.y; ph.z += pv.z; ph.w += pv.w;
                gx.x += gv.x; gx.y += gv.y; gx.z += gv.z; gx.w += gv.w;
            }
            acc += ph.x * gx.x + ph.y * gx.y + ph.z * gx.z + ph.w * gx.w;
        }
        red[t] = acc;
        __syncthreads();
        for (int off = 128; off > 0; off >>= 1) {
            if (t < off) red[t] += red[t + off];
            __syncthreads();
        }
        float s = red[0] * (1.0f / (float)HWN);
        float tb = theta_b[0];
        const float4* thp = (const float4*)th_part;
        float4* o4 = (float4*)ths;
        for (int i = t; i < HW4; i += NTHR) {
            float4 th = {tb, tb, tb, tb};
            #pragma unroll
            for (int k = 0; k < 4; ++k) {
                float4 tv = thp[(size_t)(k * BB + b) * HW4 + i];
                th.x += tv.x; th.y += tv.y; th.z += tv.z; th.w += tv.w;
            }
            float4 o = {th.x * s, th.y * s, th.z * s, th.w * s};
            o4[(size_t)b * HW4 + i] = o;
        }
    }
    __threadfence();
    grid.sync();

    // ---- Phase E: out = x + ths*A[c] + D[c] (one wave per row) ------------
    for (int r = gwid; r < BB * CCH; r += NBLK * 4) {
        int b = r >> 9, c = r & 511;
        float inv = bn_g[c] * rsqrtf(bn_v[c] + BN_EPS);
        float A = W_w[c] * inv;
        float Dc = (W_b[c] - bn_m[c]) * inv + bn_b[c];
        const float4* xr = (const float4*)x + (size_t)r * HW4;
        const float4* tr = (const float4*)ths + (size_t)b * HW4;
        f32x4* orow = (f32x4*)out + (size_t)r * HW4;
        #pragma unroll 6
        for (int k = 0; k < 18; ++k) {
            int i = lane + k * 64;
            float4 xv = xr[i];
            float4 tv = tr[i];
            f32x4 o;
            o.x = xv.x + tv.x * A + Dc;
            o.y = xv.y + tv.y * A + Dc;
            o.z = xv.z + tv.z * A + Dc;
            o.w = xv.w + tv.w * A + Dc;
            __builtin_nontemporal_store(o, &orow[i]);
        }
    }
}

// ===========================================================================
// Fallback path (proven 339 us 5-kernel version) — used only if the host-side
// capability check says cooperative launch is not viable.
// ===========================================================================
__global__ __launch_bounds__(256) void k_mean(const float* __restrict__ x,
                                              float* __restrict__ xp) {
    int wave = threadIdx.x >> 6;
    int lane = threadIdx.x & 63;
    int row = blockIdx.x * 4 + wave;
    const float4* xr = (const float4*)x + (size_t)row * HW4;
    float s = 0.f;
    #pragma unroll
    for (int k = 0; k < 18; ++k) {
        float4 v = xr[lane + k * 64];
        s += v.x + v.y + v.z + v.w;
    }
    #pragma unroll
    for (int off = 32; off > 0; off >>= 1)
        s += __shfl_down(s, off);
    if (lane == 0) xp[row] = s * (1.0f / (float)HWN);
}

__global__ __launch_bounds__(512) void k_gate(
    const float* __restrict__ xp,
    const float* __restrict__ se_w1, const float* __restrict__ se_b1,
    const float* __restrict__ se_w2, const float* __restrict__ se_b2,
    const float* __restrict__ g_w, const float* __restrict__ theta_w,
    const float* __restrict__ phi_w,
    float* __restrict__ tw, float* __restrict__ pw, float* __restrict__ gw) {
    __shared__ float xs[CCH];
    __shared__ float hs[NSE];
    int b = blockIdx.x, t = threadIdx.x;
    int wave = t >> 6, lane = t & 63;
    xs[t] = xp[b * CCH + t];
    __syncthreads();
    #pragma unroll
    for (int i = 0; i < 4; ++i) {
        int h = wave * 4 + i;
        const float* wr = se_w1 + h * CCH;
        float a = 0.f;
        #pragma unroll
        for (int k = 0; k < 8; ++k)
            a += wr[lane + 64 * k] * xs[lane + 64 * k];
        #pragma unroll
        for (int off = 32; off > 0; off >>= 1)
            a += __shfl_down(a, off);
        if (lane == 0) {
            a += se_b1[h];
            hs[h] = a > 0.f ? a : 0.f;
        }
    }
    __syncthreads();
    float a = se_b2[t];
    const float* wr = se_w2 + t * NSE;
    #pragma unroll
    for (int j = 0; j < NSE; ++j) a += wr[j] * hs[j];
    float gate = 1.f / (1.f + expf(-a));
    int idx = b * CCH + t;
    tw[idx] = gate * theta_w[t];
    pw[idx] = gate * phi_w[t];
    gw[idx] = gate * g_w[t];
}

__global__ __launch_bounds__(128) void k_proj(
    const float* __restrict__ x,
    const float* __restrict__ tw, const float* __restrict__ pw,
    const float* __restrict__ gw,
    float* __restrict__ th_part, float* __restrict__ ph_part,
    float* __restrict__ gx_part) {
    __shared__ float tws[128], pws[128], gws[128];
    int t = threadIdx.x;
    int b = blockIdx.z;
    int c0 = blockIdx.y * 128;
    int p2 = blockIdx.x * 128 + t;
    int wi = b * CCH + c0 + t;
    tws[t] = tw[wi]; pws[t] = pw[wi]; gws[t] = gw[wi];
    __syncthreads();
    const float2* xr = (const float2*)x + (size_t)(b * CCH + c0) * HW2 + p2;
    float2 tha = {0.f, 0.f}, pha = {0.f, 0.f}, gxa = {0.f, 0.f};
    #pragma unroll 8
    for (int c = 0; c < 128; ++c) {
        float2 v = xr[(size_t)c * HW2];
        float tc = tws[c], pc = pws[c], gc = gws[c];
        tha.x += tc * v.x; tha.y += tc * v.y;
        pha.x += pc * v.x; pha.y += pc * v.y;
        gxa.x += gc * v.x; gxa.y += gc * v.y;
    }
    size_t oi = (size_t)(blockIdx.y * BB + b) * HW2 + p2;
    ((float2*)th_part)[oi] = tha;
    ((float2*)ph_part)[oi] = pha;
    ((float2*)gx_part)[oi] = gxa;
}

__global__ __launch_bounds__(256) void k_scale(
    const float* __restrict__ th_part, const float* __restrict__ ph_part,
    const float* __restrict__ gx_part,
    const float* __restrict__ theta_b, const float* __restrict__ phi_b,
    const float* __restrict__ g_b,
    float* __restrict__ ths) {
    __shared__ float red[256];
    int b = blockIdx.x, t = threadIdx.x;
    float pb = phi_b[0], gb = g_b[0];
    const float4* php = (const float4*)ph_part;
    const float4* gxp = (const float4*)gx_part;
    float acc = 0.f;
    for (int i = t; i < HW4; i += 256) {
        float4 ph = {pb, pb, pb, pb};
        float4 gx = {gb, gb, gb, gb};
        #pragma unroll
        for (int k = 0; k < 4; ++k) {
            size_t oi = (size_t)(k * BB + b) * HW4 + i;
            float4 pv = php[oi];
            float4 gv = gxp[oi];
            ph.x += pv.x; ph.y += pv.y; ph.z += pv.z; ph.w += pv.w;
            gx.x += gv.x; gx.y += gv.y; gx.z += gv.z; gx.w += gv.w;
        }
        acc += ph.x * gx.x + ph.y * gx.y + ph.z * gx.z + ph.w * gx.w;
    }
    red[t] = acc;
    __syncthreads();
    for (int off = 128; off > 0; off >>= 1) {
        if (t < off) red[t] += red[t + off];
        __syncthreads();
    }
    float s = red[0] * (1.0f / (float)HWN);
    float tb = theta_b[0];
    const float4* thp = (const float4*)th_part;
    float4* out4 = (float4*)ths;
    for (int i = t; i < HW4; i += 256) {
        float4 th = {tb, tb, tb, tb};
        #pragma unroll
        for (int k = 0; k < 4; ++k) {
            float4 tv = thp[(size_t)(k * BB + b) * HW4 + i];
            th.x += tv.x; th.y += tv.y; th.z += tv.z; th.w += tv.w;
        }
        float4 o;
        o.x = th.x * s; o.y = th.y * s; o.z = th.z * s; o.w = th.w * s;
        out4[(size_t)b * HW4 + i] = o;
    }
}

__global__ __launch_bounds__(256) void k_out(
    const float* __restrict__ x, const float* __restrict__ ths,
    const float* __restrict__ W_w, const float* __restrict__ W_b,
    const float* __restrict__ bn_gamma, const float* __restrict__ bn_beta,
    const float* __restrict__ bn_mean, const float* __restrict__ bn_var,
    float* __restrict__ out) {
    int wave = threadIdx.x >> 6;
    int lane = threadIdx.x & 63;
    int c = blockIdx.x * 4 + wave;
    int b = blockIdx.y;
    float inv = bn_gamma[c] * rsqrtf(bn_var[c] + BN_EPS);
    float A = W_w[c] * inv;
    float Dc = (W_b[c] - bn_mean[c]) * inv + bn_beta[c];
    const float4* xr = (const float4*)x + (size_t)(b * CCH + c) * HW4;
    const float4* tr = (const float4*)ths + (size_t)b * HW4;
    f32x4* orow = (f32x4*)out + (size_t)(b * CCH + c) * HW4;
    #pragma unroll
    for (int k = 0; k < 18; ++k) {
        int i = lane + k * 64;
        float4 xv = xr[i];
        float4 tv = tr[i];
        f32x4 o;
        o.x = xv.x + tv.x * A + Dc;
        o.y = xv.y + tv.y * A + Dc;
        o.z = xv.z + tv.z * A + Dc;
        o.w = xv.w + tv.w * A + Dc;
        __builtin_nontemporal_store(o, &orow[i]);
    }
}

// ---------------------------------------------------------------------------
extern "C" void kernel_launch(void* const* d_in, const int* in_sizes, int n_in,
                              void* d_out, int out_size, void* d_ws, size_t ws_size,
                              hipStream_t stream) {
    const float* x       = (const float*)d_in[0];
    const float* se_w1   = (const float*)d_in[1];
    const float* se_b1   = (const float*)d_in[2];
    const float* se_w2   = (const float*)d_in[3];
    const float* se_b2   = (const float*)d_in[4];
    const float* g_w     = (const float*)d_in[5];
    const float* g_b     = (const float*)d_in[6];
    const float* theta_w = (const float*)d_in[7];
    const float* theta_b = (const float*)d_in[8];
    const float* phi_w   = (const float*)d_in[9];
    const float* phi_b   = (const float*)d_in[10];
    const float* W_w     = (const float*)d_in[11];
    const float* W_b     = (const float*)d_in[12];
    const float* bn_g    = (const float*)d_in[13];
    const float* bn_b    = (const float*)d_in[14];
    const float* bn_m    = (const float*)d_in[15];
    const float* bn_v    = (const float*)d_in[16];
    float* out = (float*)d_out;

    // workspace layout (float offsets) — ~3.96 MB
    float* ws      = (float*)d_ws;
    float* xp      = ws;                          // 8192
    float* tw      = ws + 8192;                   // 8192
    float* pw      = ws + 16384;                  // 8192
    float* gwv     = ws + 24576;                  // 8192
    float* th_part = ws + 32768;                  // 4*16*4608 = 294912
    float* ph_part = ws + 32768 + 294912;         // 294912
    float* gx_part = ws + 32768 + 2 * 294912;     // 294912
    float* ths     = ws + 32768 + 3 * 294912;     // 73728

    // Decide once from host-side queries (capture-safe, no launch attempt)
    // whether the cooperative fused path is viable on this device.
    static int coop = -1;
    if (coop < 0) {
        int nb = 0;
        hipError_t e = hipOccupancyMaxActiveBlocksPerMultiprocessor(
            &nb, (const void*)k_fused, NTHR, 0);
        int dev = 0;
        hipGetDevice(&dev);
        hipDeviceProp_t prop;
        hipError_t e2 = hipGetDeviceProperties(&prop, dev);
        coop = (e == hipSuccess && e2 == hipSuccess && prop.cooperativeLaunch &&
                nb * prop.multiProcessorCount >= NBLK) ? 1 : 0;
    }

    if (coop == 1) {
        void* args[] = {
            (void*)&x,
            (void*)&se_w1, (void*)&se_b1, (void*)&se_w2, (void*)&se_b2,
            (void*)&g_w, (void*)&g_b, (void*)&theta_w, (void*)&theta_b,
            (void*)&phi_w, (void*)&phi_b, (void*)&W_w, (void*)&W_b,
            (void*)&bn_g, (void*)&bn_b, (void*)&bn_m, (void*)&bn_v,
            (void*)&out,
            (void*)&xp, (void*)&tw, (void*)&pw, (void*)&gwv,
            (void*)&th_part, (void*)&ph_part, (void*)&gx_part, (void*)&ths
        };
        hipLaunchCooperativeKernel((const void*)k_fused, dim3(NBLK), dim3(NTHR),
                                   args, 0, stream);
        return;
    }

    // Fallback: proven 5-kernel sequence
    k_mean<<<BB * CCH / 4, 256, 0, stream>>>(x, xp);
    k_gate<<<BB, CCH, 0, stream>>>(xp, se_w1, se_b1, se_w2, se_b2,
                                   g_w, theta_w, phi_w, tw, pw, gwv);
    dim3 gc(18, 4, BB);
    k_proj<<<gc, 128, 0, stream>>>(x, tw, pw, gwv, th_part, ph_part, gx_part);
    k_scale<<<BB, 256, 0, stream>>>(th_part, ph_part, gx_part,
                                    theta_b, phi_b, g_b, ths);
    dim3 gd(CCH / 4, BB);
    k_out<<<gd, 256, 0, stream>>>(x, ths, W_w, W_b, bn_g, bn_b, bn_m, bn_v, out);
}

// Round 6
// 338.363 us; speedup vs baseline: 2.4852x; 2.4852x over previous
//
#include <hip/hip_runtime.h>
#include <math.h>

// Problem constants
#define BB   16
#define CCH  512
#define HWN  4608      // H*W = 96*48
#define HW4  1152      // HWN/4
#define HW2  2304      // HWN/2
#define NSE  32
#define BN_EPS 1e-5f

#define NCH  8         // channel chunks in k_proj
#define CPC  64        // channels per chunk

typedef float f32x4 __attribute__((ext_vector_type(4)));

// ---------------------------------------------------------------------------
// Pass 1: xp[b,c] = spatial mean. 2048 blocks x 256 thr (8 blk/CU), 1 wave/row.
// ---------------------------------------------------------------------------
__global__ __launch_bounds__(256) void k_mean(const float* __restrict__ x,
                                              float* __restrict__ xp) {
    int wave = threadIdx.x >> 6;
    int lane = threadIdx.x & 63;
    int row = blockIdx.x * 4 + wave;         // b*512 + c
    const float4* xr = (const float4*)x + (size_t)row * HW4;
    float s = 0.f;
    #pragma unroll
    for (int k = 0; k < 18; ++k) {
        float4 v = xr[lane + k * 64];
        s += v.x + v.y + v.z + v.w;
    }
    #pragma unroll
    for (int off = 32; off > 0; off >>= 1)
        s += __shfl_down(s, off);
    if (lane == 0) xp[row] = s * (1.0f / (float)HWN);
}

// ---------------------------------------------------------------------------
// Pass 2 (tiny): SE gate; emit gate-folded projection weights.
// ---------------------------------------------------------------------------
__global__ __launch_bounds__(512) void k_gate(
    const float* __restrict__ xp,
    const float* __restrict__ se_w1, const float* __restrict__ se_b1,
    const float* __restrict__ se_w2, const float* __restrict__ se_b2,
    const float* __restrict__ g_w, const float* __restrict__ theta_w,
    const float* __restrict__ phi_w,
    float* __restrict__ tw, float* __restrict__ pw, float* __restrict__ gw) {
    __shared__ float xs[CCH];
    __shared__ float hs[NSE];
    int b = blockIdx.x, t = threadIdx.x;
    int wave = t >> 6, lane = t & 63;
    xs[t] = xp[b * CCH + t];
    __syncthreads();
    #pragma unroll
    for (int i = 0; i < 4; ++i) {
        int h = wave * 4 + i;                // 8 waves x 4 = 32 hidden units
        const float* wr = se_w1 + h * CCH;
        float a = 0.f;
        #pragma unroll
        for (int k = 0; k < 8; ++k)
            a += wr[lane + 64 * k] * xs[lane + 64 * k];
        #pragma unroll
        for (int off = 32; off > 0; off >>= 1)
            a += __shfl_down(a, off);
        if (lane == 0) {
            a += se_b1[h];
            hs[h] = a > 0.f ? a : 0.f;       // relu
        }
    }
    __syncthreads();
    float a = se_b2[t];
    const float* wr = se_w2 + t * NSE;
    #pragma unroll
    for (int j = 0; j < NSE; ++j) a += wr[j] * hs[j];
    float gate = 1.f / (1.f + expf(-a));     // sigmoid
    int idx = b * CCH + t;
    tw[idx] = gate * theta_w[t];
    pw[idx] = gate * phi_w[t];
    gw[idx] = gate * g_w[t];
}

// ---------------------------------------------------------------------------
// Pass 3: partial channel contractions. grid (9, NCH=8, 16) x 256 thr
// = 1152 blocks (4.5 blk/CU, 18 waves/CU). Each block: 256 float2 p-slots,
// 64 channels serial. float2 loads, 8-deep unroll for MLP.
// ---------------------------------------------------------------------------
__global__ __launch_bounds__(256) void k_proj(
    const float* __restrict__ x,
    const float* __restrict__ tw, const float* __restrict__ pw,
    const float* __restrict__ gw,
    float* __restrict__ th_part, float* __restrict__ ph_part,
    float* __restrict__ gx_part) {
    __shared__ float tws[CPC], pws[CPC], gws[CPC];
    int t = threadIdx.x;
    int b = blockIdx.z;
    int ch = blockIdx.y;
    int c0 = ch * CPC;
    int p2 = blockIdx.x * 256 + t;           // float2 index within row
    if (t < CPC) {
        int wi = b * CCH + c0 + t;
        tws[t] = tw[wi]; pws[t] = pw[wi]; gws[t] = gw[wi];
    }
    __syncthreads();
    const float2* xr = (const float2*)x + (size_t)(b * CCH + c0) * HW2 + p2;
    float2 tha = {0.f, 0.f}, pha = {0.f, 0.f}, gxa = {0.f, 0.f};
    #pragma unroll 8
    for (int c = 0; c < CPC; ++c) {
        float2 v = xr[(size_t)c * HW2];      // 256 lanes x 8B contiguous
        float tc = tws[c], pc = pws[c], gc = gws[c];
        tha.x += tc * v.x; tha.y += tc * v.y;
        pha.x += pc * v.x; pha.y += pc * v.y;
        gxa.x += gc * v.x; gxa.y += gc * v.y;
    }
    size_t oi = (size_t)(ch * BB + b) * HW2 + p2;
    ((float2*)th_part)[oi] = tha;
    ((float2*)ph_part)[oi] = pha;
    ((float2*)gx_part)[oi] = gxa;
}

// ---------------------------------------------------------------------------
// Pass 4 (tiny): s[b] = sum_p ph*gx / n ; ths[b,p] = (th+theta_b) * s
// ---------------------------------------------------------------------------
__global__ __launch_bounds__(256) void k_scale(
    const float* __restrict__ th_part, const float* __restrict__ ph_part,
    const float* __restrict__ gx_part,
    const float* __restrict__ theta_b, const float* __restrict__ phi_b,
    const float* __restrict__ g_b,
    float* __restrict__ ths) {
    __shared__ float red[256];
    int b = blockIdx.x, t = threadIdx.x;
    float pb = phi_b[0], gb = g_b[0];
    const float4* php = (const float4*)ph_part;
    const float4* gxp = (const float4*)gx_part;
    float acc = 0.f;
    for (int i = t; i < HW4; i += 256) {
        float4 ph = {pb, pb, pb, pb};
        float4 gx = {gb, gb, gb, gb};
        #pragma unroll
        for (int k = 0; k < NCH; ++k) {
            size_t oi = (size_t)(k * BB + b) * HW4 + i;
            float4 pv = php[oi];
            float4 gv = gxp[oi];
            ph.x += pv.x; ph.y += pv.y; ph.z += pv.z; ph.w += pv.w;
            gx.x += gv.x; gx.y += gv.y; gx.z += gv.z; gx.w += gv.w;
        }
        acc += ph.x * gx.x + ph.y * gx.y + ph.z * gx.z + ph.w * gx.w;
    }
    red[t] = acc;
    __syncthreads();
    for (int off = 128; off > 0; off >>= 1) {
        if (t < off) red[t] += red[t + off];
        __syncthreads();
    }
    float s = red[0] * (1.0f / (float)HWN);
    float tb = theta_b[0];
    const float4* thp = (const float4*)th_part;
    float4* out4 = (float4*)ths;
    for (int i = t; i < HW4; i += 256) {
        float4 th = {tb, tb, tb, tb};
        #pragma unroll
        for (int k = 0; k < NCH; ++k) {
            float4 tv = thp[(size_t)(k * BB + b) * HW4 + i];
            th.x += tv.x; th.y += tv.y; th.z += tv.z; th.w += tv.w;
        }
        float4 o;
        o.x = th.x * s; o.y = th.y * s; o.z = th.z * s; o.w = th.w * s;
        out4[(size_t)b * HW4 + i] = o;
    }
}

// ---------------------------------------------------------------------------
// Pass 5: out[b,c,p] = x[b,c,p] + ths[b,p]*A[c] + D[c]
// 2048 blocks x 256 thr (8 blk/CU), one wave per channel row.
// Nontemporal stores (out streamed; keep x resident in L3).
// ---------------------------------------------------------------------------
__global__ __launch_bounds__(256) void k_out(
    const float* __restrict__ x, const float* __restrict__ ths,
    const float* __restrict__ W_w, const float* __restrict__ W_b,
    const float* __restrict__ bn_gamma, const float* __restrict__ bn_beta,
    const float* __restrict__ bn_mean, const float* __restrict__ bn_var,
    float* __restrict__ out) {
    int wave = threadIdx.x >> 6;
    int lane = threadIdx.x & 63;
    int c = blockIdx.x * 4 + wave;
    int b = blockIdx.y;
    float inv = bn_gamma[c] * rsqrtf(bn_var[c] + BN_EPS);
    float A = W_w[c] * inv;
    float Dc = (W_b[c] - bn_mean[c]) * inv + bn_beta[c];
    const float4* xr = (const float4*)x + (size_t)(b * CCH + c) * HW4;
    const float4* tr = (const float4*)ths + (size_t)b * HW4;
    f32x4* orow = (f32x4*)out + (size_t)(b * CCH + c) * HW4;
    #pragma unroll
    for (int k = 0; k < 18; ++k) {
        int i = lane + k * 64;
        float4 xv = xr[i];
        float4 tv = tr[i];
        f32x4 o;
        o.x = xv.x + tv.x * A + Dc;
        o.y = xv.y + tv.y * A + Dc;
        o.z = xv.z + tv.z * A + Dc;
        o.w = xv.w + tv.w * A + Dc;
        __builtin_nontemporal_store(o, &orow[i]);
    }
}

// ---------------------------------------------------------------------------
extern "C" void kernel_launch(void* const* d_in, const int* in_sizes, int n_in,
                              void* d_out, int out_size, void* d_ws, size_t ws_size,
                              hipStream_t stream) {
    const float* x       = (const float*)d_in[0];
    const float* se_w1   = (const float*)d_in[1];
    const float* se_b1   = (const float*)d_in[2];
    const float* se_w2   = (const float*)d_in[3];
    const float* se_b2   = (const float*)d_in[4];
    const float* g_w     = (const float*)d_in[5];
    const float* g_b     = (const float*)d_in[6];
    const float* theta_w = (const float*)d_in[7];
    const float* theta_b = (const float*)d_in[8];
    const float* phi_w   = (const float*)d_in[9];
    const float* phi_b   = (const float*)d_in[10];
    const float* W_w     = (const float*)d_in[11];
    const float* W_b     = (const float*)d_in[12];
    const float* bn_g    = (const float*)d_in[13];
    const float* bn_b    = (const float*)d_in[14];
    const float* bn_m    = (const float*)d_in[15];
    const float* bn_v    = (const float*)d_in[16];
    float* out = (float*)d_out;

    // workspace layout (float offsets) — ~7.5 MB of the ~576 MB workspace
    float* ws      = (float*)d_ws;
    float* xp      = ws;                          // 8192
    float* tw      = ws + 8192;                   // 8192
    float* pw      = ws + 16384;                  // 8192
    float* gwv     = ws + 24576;                  // 8192
    float* th_part = ws + 32768;                  // 8*16*4608 = 589824
    float* ph_part = ws + 32768 + 589824;         // 589824
    float* gx_part = ws + 32768 + 2 * 589824;     // 589824
    float* ths     = ws + 32768 + 3 * 589824;     // 73728

    k_mean<<<BB * CCH / 4, 256, 0, stream>>>(x, xp);
    k_gate<<<BB, CCH, 0, stream>>>(xp, se_w1, se_b1, se_w2, se_b2,
                                   g_w, theta_w, phi_w, tw, pw, gwv);
    dim3 gc(9, NCH, BB);
    k_proj<<<gc, 256, 0, stream>>>(x, tw, pw, gwv, th_part, ph_part, gx_part);
    k_scale<<<BB, 256, 0, stream>>>(th_part, ph_part, gx_part,
                                    theta_b, phi_b, g_b, ths);
    dim3 gd(CCH / 4, BB);
    k_out<<<gd, 256, 0, stream>>>(x, ths, W_w, W_b, bn_g, bn_b, bn_m, bn_v, out);
}